// Round 3
// baseline (715.000 us; speedup 1.0000x reference)
//
#include <hip/hip_runtime.h>
#include <hip/hip_bf16.h>
#include <cstdint>

// ---------------- config ----------------
#define TSIZE (1u << 22)
#define TMASK (TSIZE - 1u)
#define P1 2654435761u
#define P2 805459861u

typedef _Float16 f16x8 __attribute__((ext_vector_type(8)));
typedef _Float16 f16x4 __attribute__((ext_vector_type(4)));
typedef float    f32x4 __attribute__((ext_vector_type(4)));
typedef float    f32x2 __attribute__((ext_vector_type(2)));

// packed-weight layout offsets (in halfs) inside d_ws
#define W0_OFF 0        // [256][64]  (K padded 44->64)   16384
#define W1_OFF 16384    // [256][256]                     65536
#define W2_OFF 81920
#define W3_OFF 147456
#define W4_OFF 212992   // [16][256]  (rows padded 3->16)  4096
#define PACK_TOTAL 217088

// fp8 fine-table (levels 4..7) + feature buffer in d_ws
#define TB8_BYTE_OFF  524288ull
#define TB8_BYTES     (4ull * TSIZE * 4ull)          // 4 lvls * 4M * 4B = 64 MB
#define FEAT_BYTE_OFF (TB8_BYTE_OFF + TB8_BYTES)
#define FP8_SCALE     8192.0f
#define FP8_INV       (1.0f / 8192.0f)

// ------------- weight pre-pack: fp32 -> fp16 in B-fragment order -------------
__global__ __launch_bounds__(256) void convert_weights(
    const float* __restrict__ W0, const float* __restrict__ W1,
    const float* __restrict__ W2, const float* __restrict__ W3,
    const float* __restrict__ W4, _Float16* __restrict__ ws)
{
    int gid = blockIdx.x * 256 + threadIdx.x;
    if (gid >= PACK_TOTAL) return;
    const int   offs[6] = {W0_OFF, W1_OFF, W2_OFF, W3_OFF, W4_OFF, PACK_TOTAL};
    const int   outR[5] = {256, 256, 256, 256, 3};
    const int   kR[5]   = {44, 256, 256, 256, 256};
    const int   kst[5]  = {2, 8, 8, 8, 8};
    const float* Ws[5]  = {W0, W1, W2, W3, W4};
    int l = 0;
    while (gid >= offs[l + 1]) ++l;
    int local = gid - offs[l];
    int j    = local & 7;
    int lane = (local >> 3) & 63;
    int t    = local >> 9;
    int ks   = t & (kst[l] - 1);
    int cf   = t / kst[l];
    int o = cf * 16 + (lane & 15);
    int k = ks * 32 + ((lane >> 4) << 3) + j;
    float v = 0.f;
    if (o < outR[l] && k < kR[l]) v = Ws[l][o * kR[l] + k];
    ws[gid] = (_Float16)v;
}

// ------------- fp8 e4m3 encode/decode -------------
#if __has_builtin(__builtin_amdgcn_cvt_pk_fp8_f32) && __has_builtin(__builtin_amdgcn_cvt_pk_f32_fp8)
#define HAVE_FP8_CVT 1
#else
#define HAVE_FP8_CVT 0
#endif

__device__ inline uint32_t enc1_fp8(float f) {   // manual e4m3fn, fallback only
    uint32_t s = (__float_as_uint(f) >> 31) & 1u;
    float af = fabsf(f);
    if (af >= 448.f) return (s << 7) | 0x7Eu;
    uint32_t bits;
    if (af < 0.015625f) {
        uint32_t m = (uint32_t)(af * 512.0f + 0.5f);
        if (m > 7u) bits = (1u << 3);
        else bits = m;
    } else {
        int ex = (int)((__float_as_uint(af) >> 23) & 255u) - 127;
        float mant = af * exp2f((float)(-ex));
        uint32_t m = (uint32_t)((mant - 1.f) * 8.f + 0.5f);
        if (m == 8u) { m = 0u; ex++; }
        bits = ((uint32_t)(ex + 7) << 3) | m;
    }
    return (s << 7) | bits;
}
__device__ inline float dec1_fp8(uint32_t b) {   // manual e4m3fn, fallback only
    uint32_t s = (b >> 7) & 1u, e = (b >> 3) & 15u, m = b & 7u;
    float mag = (e == 0u) ? (float)m * (1.0f / 512.0f)
                          : __uint_as_float(((e + 120u) << 23) | (m << 20));
    return s ? -mag : mag;
}

__device__ inline uint32_t enc4_fp8(float4 a) {
#if HAVE_FP8_CVT
    uint32_t r = 0;
    r = __builtin_amdgcn_cvt_pk_fp8_f32(a.x * FP8_SCALE, a.y * FP8_SCALE, r, false);
    r = __builtin_amdgcn_cvt_pk_fp8_f32(a.z * FP8_SCALE, a.w * FP8_SCALE, r, true);
    return r;
#else
    return enc1_fp8(a.x * FP8_SCALE) | (enc1_fp8(a.y * FP8_SCALE) << 8) |
           (enc1_fp8(a.z * FP8_SCALE) << 16) | (enc1_fp8(a.w * FP8_SCALE) << 24);
#endif
}

// ------------- fine-table fp32 -> fp8 (levels 4..7), 2 entries/thread -------------
__global__ __launch_bounds__(256) void convert_table_fp8(
    const float* __restrict__ TBL, uint2* __restrict__ tb8)
{
    size_t t = (size_t)blockIdx.x * 256 + threadIdx.x;   // 0 .. 8M-1
    const float4* src = (const float4*)TBL + (4ull << 22) + t * 2;
    float4 a = src[0], b = src[1];
    tb8[t] = uint2{enc4_fp8(a), enc4_fp8(b)};
}

// ------------- encode kernel: one block per (256-point tile, level) -------------
__global__ __launch_bounds__(256, 4) void hash_encode(
    const float* __restrict__ X,  const float* __restrict__ WI,
    const float* __restrict__ NRM, const float* __restrict__ FD,
    const float* __restrict__ TBL, const uint32_t* __restrict__ TB8,
    _Float16* __restrict__ FEAT, int N)
{
    const int lvl = blockIdx.x & 7;
    const int p = (blockIdx.x >> 3) * 256 + threadIdx.x;
    if (p >= N) return;

    float x0 = X[p * 3 + 0], x1 = X[p * 3 + 1], x2 = X[p * 3 + 2];
    float res = (float)(16 << lvl);
    float px = x0 * res, py = x1 * res, pz = x2 * res;
    float fx = floorf(px), fy = floorf(py), fz = floorf(pz);
    float wx = px - fx, wy = py - fy, wz = pz - fz;
    float ux = 1.f - wx, uy = 1.f - wy, uz = 1.f - wz;
    uint32_t hx0 = (uint32_t)(int)fx, hx1 = hx0 + 1u;
    uint32_t hy0 = (uint32_t)(int)fy * P1, hy1 = hy0 + P1;
    uint32_t hz0 = (uint32_t)(int)fz * P2, hz1 = hz0 + P2;

    float a0 = 0.f, a1 = 0.f, a2 = 0.f, a3 = 0.f;
    if (lvl >= 4) {
        const uint32_t* tl = TB8 + ((size_t)(lvl - 4) << 22);
        #pragma unroll
        for (int c = 0; c < 8; ++c) {
            uint32_t h = ((c & 4) ? hx1 : hx0) ^ ((c & 2) ? hy1 : hy0) ^ ((c & 1) ? hz1 : hz0);
            uint32_t g = tl[h & TMASK];
            float cw = ((c & 4) ? wx : ux) * ((c & 2) ? wy : uy) * ((c & 1) ? wz : uz) * FP8_INV;
#if HAVE_FP8_CVT
            f32x2 lo = __builtin_amdgcn_cvt_pk_f32_fp8(g, false);
            f32x2 hi = __builtin_amdgcn_cvt_pk_f32_fp8(g, true);
            a0 += lo.x * cw; a1 += lo.y * cw; a2 += hi.x * cw; a3 += hi.y * cw;
#else
            a0 += dec1_fp8(g & 255u) * cw;         a1 += dec1_fp8((g >> 8) & 255u) * cw;
            a2 += dec1_fp8((g >> 16) & 255u) * cw; a3 += dec1_fp8(g >> 24) * cw;
#endif
        }
    } else {
        const float4* tl = (const float4*)TBL + ((size_t)lvl << 22);
        #pragma unroll
        for (int c = 0; c < 8; ++c) {
            uint32_t h = ((c & 4) ? hx1 : hx0) ^ ((c & 2) ? hy1 : hy0) ^ ((c & 1) ? hz1 : hz0);
            float4 g = tl[h & TMASK];
            float cw = ((c & 4) ? wx : ux) * ((c & 2) ? wy : uy) * ((c & 1) ? wz : uz);
            a0 += g.x * cw; a1 += g.y * cw; a2 += g.z * cw; a3 += g.w * cw;
        }
    }
    _Float16* row = FEAT + (size_t)p * 64;
    *(f16x4*)(row + 12 + lvl * 4) = f16x4{(_Float16)a0, (_Float16)a1, (_Float16)a2, (_Float16)a3};
    if (lvl == 0) {
        *(f16x4*)(row + 0) = f16x4{(_Float16)x0, (_Float16)x1, (_Float16)x2, (_Float16)WI[p * 3]};
        *(f16x4*)(row + 4) = f16x4{(_Float16)WI[p * 3 + 1], (_Float16)WI[p * 3 + 2],
                                   (_Float16)NRM[p * 3], (_Float16)NRM[p * 3 + 1]};
        *(f16x4*)(row + 8) = f16x4{(_Float16)NRM[p * 3 + 2], (_Float16)FD[p * 3],
                                   (_Float16)FD[p * 3 + 1], (_Float16)FD[p * 3 + 2]};
        f16x4 z{(_Float16)0.f, (_Float16)0.f, (_Float16)0.f, (_Float16)0.f};
        #pragma unroll
        for (int cc = 44; cc < 64; cc += 4) *(f16x4*)(row + cc) = z;
    }
}

// ------------- MLP kernel: 128 points / 512 threads / 8 waves -------------
// A-frag (m x k): lane holds act[row = l&15][k = ks*32 + (l>>4)*8 + j]
// B-frag (k x n): lane holds W[col = l&15][same k]  (pre-packed)
// D-frag:         lane holds D[row = (l>>4)*4 + r][col = l&15]
template <int KSTEPS, int SSTRIDE, bool GSRC>
__device__ inline void mlp_layer8(const char* __restrict__ src, char* __restrict__ dst,
                                  const f16x8* __restrict__ wp, const float* __restrict__ bias,
                                  int wave, int lane, bool relu)
{
    f32x4 acc[8][2];
    #pragma unroll
    for (int i = 0; i < 8; ++i) {
        acc[i][0] = f32x4{0.f, 0.f, 0.f, 0.f};
        acc[i][1] = f32x4{0.f, 0.f, 0.f, 0.f};
    }
    const int cf0 = wave * 2;
    #pragma unroll 2
    for (int ks = 0; ks < KSTEPS; ++ks) {
        f16x8 b0 = wp[(cf0 * KSTEPS + ks) * 64 + lane];
        f16x8 b1 = wp[((cf0 + 1) * KSTEPS + ks) * 64 + lane];
        int kb = ks * 64 + ((lane >> 4) << 4);
        #pragma unroll
        for (int rf = 0; rf < 8; ++rf) {
            int row = rf * 16 + (lane & 15);
            int off = GSRC ? (row * SSTRIDE + kb)
                           : (row * SSTRIDE + (kb ^ ((row & 7) << 4)));
            f16x8 a = *(const f16x8*)(src + off);
            acc[rf][0] = __builtin_amdgcn_mfma_f32_16x16x32_f16(a, b0, acc[rf][0], 0, 0, 0);
            acc[rf][1] = __builtin_amdgcn_mfma_f32_16x16x32_f16(a, b1, acc[rf][1], 0, 0, 0);
        }
    }
    #pragma unroll
    for (int c = 0; c < 2; ++c) {
        int col = wave * 32 + c * 16 + (lane & 15);
        float bv = bias[col];
        #pragma unroll
        for (int rf = 0; rf < 8; ++rf) {
            #pragma unroll
            for (int r = 0; r < 4; ++r) {
                int row = rf * 16 + ((lane >> 4) << 2) + r;
                float v = acc[rf][c][r] + bv;
                if (relu) v = fmaxf(v, 0.f);
                *(_Float16*)(dst + row * 512 + ((col * 2) ^ ((row & 7) << 4))) = (_Float16)v;
            }
        }
    }
}

#define MLP_SMEM 131072

__global__ __launch_bounds__(512, 2) void mlp_mfma(
    const _Float16* __restrict__ FEAT,
    const float* __restrict__ B0, const float* __restrict__ B1,
    const float* __restrict__ B2, const float* __restrict__ B3,
    const float* __restrict__ B4,
    const _Float16* __restrict__ WS,
    float* __restrict__ OUT, int N)
{
    extern __shared__ char smem[];
    char* actA = smem;
    char* actB = smem + 65536;

    const int tid  = threadIdx.x;
    const int wave = tid >> 6, lane = tid & 63;
    const size_t brow = (size_t)blockIdx.x * 128;
    const char* feat = (const char*)(FEAT + brow * 64);

    mlp_layer8<2, 128, true >(feat, actA, (const f16x8*)(WS + W0_OFF), B0, wave, lane, true);
    __syncthreads();
    mlp_layer8<8, 512, false>(actA, actB, (const f16x8*)(WS + W1_OFF), B1, wave, lane, true);
    __syncthreads();
    mlp_layer8<8, 512, false>(actB, actA, (const f16x8*)(WS + W2_OFF), B2, wave, lane, true);
    __syncthreads();
    mlp_layer8<8, 512, false>(actA, actB, (const f16x8*)(WS + W3_OFF), B3, wave, lane, true);
    __syncthreads();

    // final layer: each wave owns a 16-row stripe, cols 0..15 (3 real)
    f32x4 acc = f32x4{0.f, 0.f, 0.f, 0.f};
    const f16x8* wp4 = (const f16x8*)(WS + W4_OFF);
    {
        int row = wave * 16 + (lane & 15);
        #pragma unroll
        for (int ks = 0; ks < 8; ++ks) {
            f16x8 b = wp4[ks * 64 + lane];
            int kb = ks * 64 + ((lane >> 4) << 4);
            f16x8 a = *(const f16x8*)(actB + row * 512 + (kb ^ ((row & 7) << 4)));
            acc = __builtin_amdgcn_mfma_f32_16x16x32_f16(a, b, acc, 0, 0, 0);
        }
    }
    int col = lane & 15;
    if (col < 3) {
        float bv = B4[col];
        #pragma unroll
        for (int r = 0; r < 4; ++r) {
            int row = wave * 16 + ((lane >> 4) << 2) + r;
            size_t g = brow + row;
            if (g < (size_t)N) OUT[g * 3 + col] = fabsf(acc[r] + bv);
        }
    }
}

// ================= fallback: round-2 fused kernel (fp32 tables only) =================
#define FB_FEAT_OFF 0
#define FB_ACTA_OFF 8192
#define FB_ACTB_OFF 40960
#define FB_SMEM 73728

template <int KSTEPS, int SSTRIDE>
__device__ inline void mlp_layer4(const char* __restrict__ src, char* __restrict__ dst,
                                  const f16x8* __restrict__ wp, const float* __restrict__ bias,
                                  int wave, int lane, bool relu)
{
    f32x4 acc[4][4];
    #pragma unroll
    for (int i = 0; i < 4; ++i)
        #pragma unroll
        for (int c = 0; c < 4; ++c)
            acc[i][c] = f32x4{0.f, 0.f, 0.f, 0.f};
    const int cf0 = wave * 4;
    #pragma unroll 2
    for (int ks = 0; ks < KSTEPS; ++ks) {
        f16x8 b[4];
        #pragma unroll
        for (int c = 0; c < 4; ++c)
            b[c] = wp[((cf0 + c) * KSTEPS + ks) * 64 + lane];
        int kb = ks * 64 + ((lane >> 4) << 4);
        #pragma unroll
        for (int rf = 0; rf < 4; ++rf) {
            int row = rf * 16 + (lane & 15);
            f16x8 a = *(const f16x8*)(src + row * SSTRIDE + (kb ^ ((row & 7) << 4)));
            #pragma unroll
            for (int c = 0; c < 4; ++c)
                acc[rf][c] = __builtin_amdgcn_mfma_f32_16x16x32_f16(a, b[c], acc[rf][c], 0, 0, 0);
        }
    }
    #pragma unroll
    for (int rf = 0; rf < 4; ++rf) {
        #pragma unroll
        for (int c = 0; c < 4; ++c) {
            int col = wave * 64 + c * 16 + (lane & 15);
            float bv = bias[col];
            #pragma unroll
            for (int r = 0; r < 4; ++r) {
                int row = rf * 16 + ((lane >> 4) << 2) + r;
                float v = acc[rf][c][r] + bv;
                if (relu) v = fmaxf(v, 0.f);
                *(_Float16*)(dst + row * 512 + ((col * 2) ^ ((row & 7) << 4))) = (_Float16)v;
            }
        }
    }
}

__global__ __launch_bounds__(256, 2) void nrfield_fused(
    const float* __restrict__ X,  const float* __restrict__ WI,
    const float* __restrict__ NRM, const float* __restrict__ FD,
    const float* __restrict__ TBL,
    const float* __restrict__ B0, const float* __restrict__ B1,
    const float* __restrict__ B2, const float* __restrict__ B3,
    const float* __restrict__ B4,
    const _Float16* __restrict__ WS,
    float* __restrict__ OUT, int N)
{
    extern __shared__ char smem[];
    char* feat = smem + FB_FEAT_OFF;
    char* actA = smem + FB_ACTA_OFF;
    char* actB = smem + FB_ACTB_OFF;

    const int tid  = threadIdx.x;
    const int wave = tid >> 6, lane = tid & 63;
    const int p = lane;
    const int gp = blockIdx.x * 64 + p;

    auto fw4 = [&](int row, int col, f16x4 v) {
        *(f16x4*)(feat + row * 128 + ((col * 2) ^ ((row & 7) << 4))) = v;
    };

    if (gp < N) {
        float x0 = X[gp * 3 + 0], x1 = X[gp * 3 + 1], x2 = X[gp * 3 + 2];
        #pragma unroll
        for (int s = 0; s < 2; ++s) {
            int lvl = wave * 2 + s;
            float res = (float)(16 << lvl);
            float px = x0 * res, py = x1 * res, pz = x2 * res;
            float fx = floorf(px), fy = floorf(py), fz = floorf(pz);
            float wx = px - fx, wy = py - fy, wz = pz - fz;
            float ux = 1.f - wx, uy = 1.f - wy, uz = 1.f - wz;
            uint32_t hx0 = (uint32_t)(int)fx, hx1 = hx0 + 1u;
            uint32_t hy0 = (uint32_t)(int)fy * P1, hy1 = hy0 + P1;
            uint32_t hz0 = (uint32_t)(int)fz * P2, hz1 = hz0 + P2;
            const float4* tl = (const float4*)TBL + ((size_t)lvl << 22);
            float a0 = 0.f, a1 = 0.f, a2 = 0.f, a3 = 0.f;
            #pragma unroll
            for (int c = 0; c < 8; ++c) {
                uint32_t h = ((c & 4) ? hx1 : hx0) ^ ((c & 2) ? hy1 : hy0) ^ ((c & 1) ? hz1 : hz0);
                float4 g = tl[h & TMASK];
                float cw = ((c & 4) ? wx : ux) * ((c & 2) ? wy : uy) * ((c & 1) ? wz : uz);
                a0 += g.x * cw; a1 += g.y * cw; a2 += g.z * cw; a3 += g.w * cw;
            }
            fw4(p, 12 + lvl * 4, f16x4{(_Float16)a0, (_Float16)a1, (_Float16)a2, (_Float16)a3});
        }
        if (wave == 0) {
            fw4(p, 0, f16x4{(_Float16)x0, (_Float16)x1, (_Float16)x2, (_Float16)WI[gp * 3]});
            fw4(p, 4, f16x4{(_Float16)WI[gp * 3 + 1], (_Float16)WI[gp * 3 + 2],
                            (_Float16)NRM[gp * 3], (_Float16)NRM[gp * 3 + 1]});
            fw4(p, 8, f16x4{(_Float16)NRM[gp * 3 + 2], (_Float16)FD[gp * 3],
                            (_Float16)FD[gp * 3 + 1], (_Float16)FD[gp * 3 + 2]});
            f16x4 z{(_Float16)0.f, (_Float16)0.f, (_Float16)0.f, (_Float16)0.f};
            #pragma unroll
            for (int cc = 44; cc < 64; cc += 4) fw4(p, cc, z);
        }
    }
    __syncthreads();

    mlp_layer4<2, 128>(feat, actA, (const f16x8*)(WS + W0_OFF), B0, wave, lane, true);
    __syncthreads();
    mlp_layer4<8, 512>(actA, actB, (const f16x8*)(WS + W1_OFF), B1, wave, lane, true);
    __syncthreads();
    mlp_layer4<8, 512>(actB, actA, (const f16x8*)(WS + W2_OFF), B2, wave, lane, true);
    __syncthreads();
    mlp_layer4<8, 512>(actA, actB, (const f16x8*)(WS + W3_OFF), B3, wave, lane, true);
    __syncthreads();

    f32x4 acc = f32x4{0.f, 0.f, 0.f, 0.f};
    const f16x8* wp4 = (const f16x8*)(WS + W4_OFF);
    {
        int row = wave * 16 + (lane & 15);
        #pragma unroll
        for (int ks = 0; ks < 8; ++ks) {
            f16x8 b = wp4[ks * 64 + lane];
            int kb = ks * 64 + ((lane >> 4) << 4);
            f16x8 a = *(const f16x8*)(actB + row * 512 + (kb ^ ((row & 7) << 4)));
            acc = __builtin_amdgcn_mfma_f32_16x16x32_f16(a, b, acc, 0, 0, 0);
        }
    }
    int col = lane & 15;
    if (col < 3) {
        float bv = B4[col];
        #pragma unroll
        for (int r = 0; r < 4; ++r) {
            int row = wave * 16 + ((lane >> 4) << 2) + r;
            int g = blockIdx.x * 64 + row;
            if (g < N) OUT[g * 3 + col] = fabsf(acc[r] + bv);
        }
    }
}

// ================= launch =================
extern "C" void kernel_launch(void* const* d_in, const int* in_sizes, int n_in,
                              void* d_out, int out_size, void* d_ws, size_t ws_size,
                              hipStream_t stream)
{
    const float* X   = (const float*)d_in[0];
    const float* WI  = (const float*)d_in[1];
    const float* NRM = (const float*)d_in[2];
    const float* FD  = (const float*)d_in[3];
    const float* TBL = (const float*)d_in[4];
    const float* W0  = (const float*)d_in[5];
    const float* B0  = (const float*)d_in[6];
    const float* W1  = (const float*)d_in[7];
    const float* B1  = (const float*)d_in[8];
    const float* W2  = (const float*)d_in[9];
    const float* B2  = (const float*)d_in[10];
    const float* W3  = (const float*)d_in[11];
    const float* B3  = (const float*)d_in[12];
    const float* W4  = (const float*)d_in[13];
    const float* B4  = (const float*)d_in[14];
    float* OUT = (float*)d_out;

    int N = in_sizes[0] / 3;
    _Float16* ws = (_Float16*)d_ws;

    convert_weights<<<(PACK_TOTAL + 255) / 256, 256, 0, stream>>>(W0, W1, W2, W3, W4, ws);

    size_t need = FEAT_BYTE_OFF + (size_t)N * 128;
    if (ws_size >= need) {
        uint32_t* tb8 = (uint32_t*)((char*)d_ws + TB8_BYTE_OFF);
        _Float16* feat = (_Float16*)((char*)d_ws + FEAT_BYTE_OFF);
        convert_table_fp8<<<32768, 256, 0, stream>>>(TBL, (uint2*)tb8);
        int nPB = (N + 255) / 256;
        hash_encode<<<nPB * 8, 256, 0, stream>>>(X, WI, NRM, FD, TBL, tb8, feat, N);
        hipFuncSetAttribute((const void*)mlp_mfma,
                            hipFuncAttributeMaxDynamicSharedMemorySize, MLP_SMEM);
        mlp_mfma<<<(N + 127) / 128, 512, MLP_SMEM, stream>>>(feat, B0, B1, B2, B3, B4,
                                                             ws, OUT, N);
    } else {
        hipFuncSetAttribute((const void*)nrfield_fused,
                            hipFuncAttributeMaxDynamicSharedMemorySize, FB_SMEM);
        int grid = (N + 63) / 64;
        nrfield_fused<<<grid, 256, FB_SMEM, stream>>>(X, WI, NRM, FD, TBL,
                                                      B0, B1, B2, B3, B4, ws, OUT, N);
    }
}

// Round 4
// 670.377 us; speedup vs baseline: 1.0666x; 1.0666x over previous
//
#include <hip/hip_runtime.h>
#include <hip/hip_bf16.h>
#include <cstdint>

// ---------------- config ----------------
#define TSIZE (1u << 22)
#define TMASK (TSIZE - 1u)
#define P1 2654435761u
#define P2 805459861u

typedef _Float16 f16x8 __attribute__((ext_vector_type(8)));
typedef _Float16 f16x4 __attribute__((ext_vector_type(4)));
typedef float    f32x4 __attribute__((ext_vector_type(4)));
typedef float    f32x2 __attribute__((ext_vector_type(2)));

// packed-weight layout offsets (in halfs) inside d_ws
#define W0_OFF 0        // [256][64]  (K padded; remapped feature order)
#define W1_OFF 16384
#define W2_OFF 81920
#define W3_OFF 147456
#define W4_OFF 212992   // [16][256] (rows padded 3->16)
#define PACK_TOTAL 217088

// fp8 tables, ALL 8 levels, in d_ws
#define TB8_BYTE_OFF 524288ull
#define TB8_BYTES    (8ull * TSIZE * 4ull)      // 128 MB
#define WS_NEED      (TB8_BYTE_OFF + TB8_BYTES) // ~128.5 MB (proven available)
#define FP8_SCALE    8192.0f
#define FP8_INV      (1.0f / 8192.0f)

// LDS layout (bytes): feat [64][128B], actA/actB [64][512B]
#define FEAT_OFF 0
#define ACTA_OFF 8192
#define ACTB_OFF 40960
#define SMEM_BYTES 73728   // 72 KB -> 2 blocks/CU

// feature order (new): col 0..31 = grid feats (lvl*4+f), 32..43 = inputs
// (x,wi,n,f_d comps), 44..63 = zero pad.

// LDS swizzle: reads 2-way (free), b16 epilogue writes 2-way (free)
__device__ inline int swz(int row) {
    return (((row >> 2) & 3) << 5) | ((row & 1) << 4);
}

// lgkm-only barrier: leaves global loads (gather pipeline) in flight
__device__ inline void lbar() {
    asm volatile("s_waitcnt lgkmcnt(0)" ::: "memory");
    __builtin_amdgcn_s_barrier();
    asm volatile("" ::: "memory");
}

// ------------- weight pre-pack: fp32 -> fp16 in B-fragment order -------------
__global__ __launch_bounds__(256) void convert_weights(
    const float* __restrict__ W0, const float* __restrict__ W1,
    const float* __restrict__ W2, const float* __restrict__ W3,
    const float* __restrict__ W4, _Float16* __restrict__ ws)
{
    int gid = blockIdx.x * 256 + threadIdx.x;
    if (gid >= PACK_TOTAL) return;
    const int   offs[6] = {W0_OFF, W1_OFF, W2_OFF, W3_OFF, W4_OFF, PACK_TOTAL};
    const int   outR[5] = {256, 256, 256, 256, 3};
    const int   kR[5]   = {44, 256, 256, 256, 256};
    const int   kst[5]  = {2, 8, 8, 8, 8};
    const float* Ws[5]  = {W0, W1, W2, W3, W4};
    int l = 0;
    while (gid >= offs[l + 1]) ++l;
    int local = gid - offs[l];
    int j    = local & 7;
    int lane = (local >> 3) & 63;
    int t    = local >> 9;
    int ks   = t & (kst[l] - 1);
    int cf   = t / kst[l];
    int o = cf * 16 + (lane & 15);
    int k = ks * 32 + ((lane >> 4) << 3) + j;
    float v = 0.f;
    if (l == 0) {
        // new feature order: k<32 -> grid feat (old col 12+k); 32..43 -> old col k-32
        int kk = (k < 32) ? (12 + k) : ((k < 44) ? (k - 32) : -1);
        if (o < 256 && kk >= 0) v = W0[o * 44 + kk];
    } else {
        if (o < outR[l] && k < kR[l]) v = Ws[l][o * kR[l] + k];
    }
    ws[gid] = (_Float16)v;
}

// ------------- fp8 e4m3 encode -------------
#if __has_builtin(__builtin_amdgcn_cvt_pk_fp8_f32) && __has_builtin(__builtin_amdgcn_cvt_pk_f32_fp8)
#define HAVE_FP8_CVT 1
#else
#define HAVE_FP8_CVT 0
#endif

__device__ inline uint32_t enc1_fp8(float f) {   // manual e4m3fn, fallback only
    uint32_t s = (__float_as_uint(f) >> 31) & 1u;
    float af = fabsf(f);
    if (af >= 448.f) return (s << 7) | 0x7Eu;
    uint32_t bits;
    if (af < 0.015625f) {
        uint32_t m = (uint32_t)(af * 512.0f + 0.5f);
        bits = (m > 7u) ? (1u << 3) : m;
    } else {
        int ex = (int)((__float_as_uint(af) >> 23) & 255u) - 127;
        float mant = af * exp2f((float)(-ex));
        uint32_t m = (uint32_t)((mant - 1.f) * 8.f + 0.5f);
        if (m == 8u) { m = 0u; ex++; }
        bits = ((uint32_t)(ex + 7) << 3) | m;
    }
    return (s << 7) | bits;
}

__device__ inline uint32_t enc4_fp8(f32x4 a) {
#if HAVE_FP8_CVT
    uint32_t r = 0;
    r = __builtin_amdgcn_cvt_pk_fp8_f32(a.x * FP8_SCALE, a.y * FP8_SCALE, r, false);
    r = __builtin_amdgcn_cvt_pk_fp8_f32(a.z * FP8_SCALE, a.w * FP8_SCALE, r, true);
    return r;
#else
    return enc1_fp8(a.x * FP8_SCALE) | (enc1_fp8(a.y * FP8_SCALE) << 8) |
           (enc1_fp8(a.z * FP8_SCALE) << 16) | (enc1_fp8(a.w * FP8_SCALE) << 24);
#endif
}

// ------------- table fp32 -> fp8, all 8 levels, 2 entries/thread -------------
// nontemporal reads: the 512 MB stream must not flush L3 (fp8 tables live there)
__global__ __launch_bounds__(256) void convert_table8(
    const float* __restrict__ TBL, uint2* __restrict__ tb8)
{
    size_t t = (size_t)blockIdx.x * 256 + threadIdx.x;   // 0 .. 16.8M-1
    const f32x4* src = (const f32x4*)TBL + t * 2;
    f32x4 a = __builtin_nontemporal_load(src);
    f32x4 b = __builtin_nontemporal_load(src + 1);
    tb8[t] = uint2{enc4_fp8(a), enc4_fp8(b)};
}

// ------------- MLP layer: 4 waves, 64 points, acc[4][4] -------------
// A-frag: lane holds act[row=l&15][k = ks*32+(l>>4)*8+j]; B pre-packed; 
// D: row=(l>>4)*4+r, col=l&15
template <int KSTEPS, int SSTR>
__device__ inline void layer4w(const char* __restrict__ src, char* __restrict__ dst,
                               const f16x8* __restrict__ wp, const float* __restrict__ bv,
                               int wave, int lane)
{
    f32x4 acc[4][4];
    #pragma unroll
    for (int i = 0; i < 4; ++i)
        #pragma unroll
        for (int c = 0; c < 4; ++c)
            acc[i][c] = f32x4{0.f, 0.f, 0.f, 0.f};
    const int cf0 = wave * 4;
    #pragma unroll 2
    for (int ks = 0; ks < KSTEPS; ++ks) {
        f16x8 b[4];
        #pragma unroll
        for (int c = 0; c < 4; ++c)
            b[c] = wp[((cf0 + c) * KSTEPS + ks) * 64 + lane];
        int kb = ks * 64 + ((lane >> 4) << 4);
        #pragma unroll
        for (int rf = 0; rf < 4; ++rf) {
            int row = rf * 16 + (lane & 15);
            f16x8 a = *(const f16x8*)(src + row * SSTR + (kb ^ swz(row)));
            #pragma unroll
            for (int c = 0; c < 4; ++c)
                acc[rf][c] = __builtin_amdgcn_mfma_f32_16x16x32_f16(a, b[c], acc[rf][c], 0, 0, 0);
        }
    }
    #pragma unroll
    for (int rf = 0; rf < 4; ++rf) {
        #pragma unroll
        for (int c = 0; c < 4; ++c) {
            int col = wave * 64 + c * 16 + (lane & 15);
            #pragma unroll
            for (int r = 0; r < 4; ++r) {
                int row = rf * 16 + ((lane >> 4) << 2) + r;
                float v = fmaxf(acc[rf][c][r] + bv[c], 0.f);
                *(_Float16*)(dst + row * 512 + ((col * 2) ^ swz(row))) = (_Float16)v;
            }
        }
    }
}

// ------------- fused persistent kernel: encode pipeline + MLP -------------
__global__ __launch_bounds__(256, 2) void nrfield_pipe(
    const float* __restrict__ X,  const float* __restrict__ WI,
    const float* __restrict__ NRM, const float* __restrict__ FD,
    const uint32_t* __restrict__ TB8,
    const float* __restrict__ B0, const float* __restrict__ B1,
    const float* __restrict__ B2, const float* __restrict__ B3,
    const float* __restrict__ B4,
    const _Float16* __restrict__ WS,
    float* __restrict__ OUT, int N, int CH)
{
    extern __shared__ char smem[];
    char* feat = smem + FEAT_OFF;
    char* actA = smem + ACTA_OFF;
    char* actB = smem + ACTB_OFF;

    const int tid  = threadIdx.x;
    const int wave = tid >> 6, lane = tid & 63;
    const int p = lane;
    const long blkBase = (long)blockIdx.x * CH * 64;

    // zero-pad feat cols 44..63 (bytes 88..127) once; never rewritten
    {
        uint4 z4{0, 0, 0, 0};
        if (wave == 0) *(uint2*)(feat + p * 128 + (88 ^ swz(p))) = uint2{0, 0};
        if (wave == 1) *(uint4*)(feat + p * 128 + (96 ^ swz(p))) = z4;
        if (wave == 2) *(uint4*)(feat + p * 128 + (112 ^ swz(p))) = z4;
    }

    // per-thread bias registers
    float bL0[4], bL1[4], bL2[4], bL3[4];
    #pragma unroll
    for (int c = 0; c < 4; ++c) {
        int col = wave * 64 + c * 16 + (lane & 15);
        bL0[c] = B0[col]; bL1[c] = B1[col]; bL2[c] = B2[col]; bL3[c] = B3[col];
    }
    const int ocol = lane & 15;
    float b4v = (ocol < 3) ? B4[ocol] : 0.f;

    const float* auxp = (wave == 0) ? X : (wave == 1) ? WI : (wave == 2) ? NRM : FD;

    auto clampP = [&](long g) { long m = (long)N - 1; return (g < m) ? g : m; };

    // pipeline state
    float xc0, xc1, xc2, aux0, aux1, aux2;       // inputs for chunk ci
    float xn0, xn1, xn2, axn0, axn1, axn2;       // inputs for chunk ci+1 (in flight)
    uint32_t g[16];                              // fp8 gathers for chunk ci

    // gather-issue: 2 levels (2*wave, 2*wave+1), 8 corners each
    auto issue_gathers = [&](float x0, float x1, float x2) {
        #pragma unroll
        for (int s = 0; s < 2; ++s) {
            int lvl = wave * 2 + s;
            float res = (float)(16 << lvl);
            float px = x0 * res, py = x1 * res, pz = x2 * res;
            uint32_t hx0 = (uint32_t)(int)floorf(px), hx1 = hx0 + 1u;
            uint32_t hy0 = (uint32_t)(int)floorf(py) * P1, hy1 = hy0 + P1;
            uint32_t hz0 = (uint32_t)(int)floorf(pz) * P2, hz1 = hz0 + P2;
            const uint32_t* tl = TB8 + ((size_t)lvl << 22);
            #pragma unroll
            for (int c = 0; c < 8; ++c) {
                uint32_t h = ((c & 4) ? hx1 : hx0) ^ ((c & 2) ? hy1 : hy0) ^ ((c & 1) ? hz1 : hz0);
                g[s * 8 + c] = tl[h & TMASK];
            }
        }
    };

    // prologue: inputs(0), gathers(0), inputs(1)
    {
        long g0 = clampP(blkBase + p);
        xc0 = X[g0 * 3]; xc1 = X[g0 * 3 + 1]; xc2 = X[g0 * 3 + 2];
        aux0 = auxp[g0 * 3]; aux1 = auxp[g0 * 3 + 1]; aux2 = auxp[g0 * 3 + 2];
        issue_gathers(xc0, xc1, xc2);
        long g1 = clampP(blkBase + 64 + p);
        xn0 = X[g1 * 3]; xn1 = X[g1 * 3 + 1]; xn2 = X[g1 * 3 + 2];
        axn0 = auxp[g1 * 3]; axn1 = auxp[g1 * 3 + 1]; axn2 = auxp[g1 * 3 + 2];
    }

    for (int ci = 0; ci < CH; ++ci) {
        // ---- trilinear combine for chunk ci (gathers already in flight) ----
        f16x8 fv;
        #pragma unroll
        for (int s = 0; s < 2; ++s) {
            int lvl = wave * 2 + s;
            float res = (float)(16 << lvl);
            float px = xc0 * res, py = xc1 * res, pz = xc2 * res;
            float wx = px - floorf(px), wy = py - floorf(py), wz = pz - floorf(pz);
            float ux = 1.f - wx, uy = 1.f - wy, uz = 1.f - wz;
            float a0 = 0.f, a1 = 0.f, a2 = 0.f, a3 = 0.f;
            #pragma unroll
            for (int c = 0; c < 8; ++c) {
                uint32_t gg = g[s * 8 + c];
                float cw = ((c & 4) ? wx : ux) * ((c & 2) ? wy : uy) * ((c & 1) ? wz : uz) * FP8_INV;
#if HAVE_FP8_CVT
                f32x2 lo = __builtin_amdgcn_cvt_pk_f32_fp8(gg, false);
                f32x2 hi = __builtin_amdgcn_cvt_pk_f32_fp8(gg, true);
                a0 += lo.x * cw; a1 += lo.y * cw; a2 += hi.x * cw; a3 += hi.y * cw;
#else
                a0 += 0.f;  // (unreachable on gfx950)
#endif
            }
            fv[s * 4 + 0] = (_Float16)a0; fv[s * 4 + 1] = (_Float16)a1;
            fv[s * 4 + 2] = (_Float16)a2; fv[s * 4 + 3] = (_Float16)a3;
        }
        *(f16x8*)(feat + p * 128 + ((wave * 16) ^ swz(p))) = fv;
        // input features: wave w writes comps 3w..3w+2 (cols 32+3w..)
        {
            int cb = (32 + wave * 3) * 2;
            *(_Float16*)(feat + p * 128 + ((cb    ) ^ swz(p))) = (_Float16)aux0;
            *(_Float16*)(feat + p * 128 + ((cb + 2) ^ swz(p))) = (_Float16)aux1;
            *(_Float16*)(feat + p * 128 + ((cb + 4) ^ swz(p))) = (_Float16)aux2;
        }

        // ---- rotate inputs; issue gathers(ci+1); issue loads(ci+2) ----
        xc0 = xn0; xc1 = xn1; xc2 = xn2;
        aux0 = axn0; aux1 = axn1; aux2 = axn2;
        issue_gathers(xc0, xc1, xc2);            // in flight across the whole MLP
        {
            long g2 = clampP(blkBase + (long)(ci + 2) * 64 + p);
            xn0 = X[g2 * 3]; xn1 = X[g2 * 3 + 1]; xn2 = X[g2 * 3 + 2];
            axn0 = auxp[g2 * 3]; axn1 = auxp[g2 * 3 + 1]; axn2 = auxp[g2 * 3 + 2];
        }

        lbar();   // feat ready (lgkm only -- gathers stay in flight)

        // ---- MLP for chunk ci ----
        layer4w<2, 128>(feat, actA, (const f16x8*)(WS + W0_OFF), bL0, wave, lane);
        lbar();
        layer4w<8, 512>(actA, actB, (const f16x8*)(WS + W1_OFF), bL1, wave, lane);
        lbar();
        layer4w<8, 512>(actB, actA, (const f16x8*)(WS + W2_OFF), bL2, wave, lane);
        lbar();
        layer4w<8, 512>(actA, actB, (const f16x8*)(WS + W3_OFF), bL3, wave, lane);
        lbar();

        // final layer: wave owns rows wave*16..+15, cols 0..15 (3 real)
        f32x4 acc = f32x4{0.f, 0.f, 0.f, 0.f};
        const f16x8* wp4 = (const f16x8*)(WS + W4_OFF);
        {
            int row = wave * 16 + (lane & 15);
            #pragma unroll
            for (int ks = 0; ks < 8; ++ks) {
                f16x8 b = wp4[ks * 64 + lane];
                int kb = ks * 64 + ((lane >> 4) << 4);
                f16x8 a = *(const f16x8*)(actB + row * 512 + (kb ^ swz(row)));
                acc = __builtin_amdgcn_mfma_f32_16x16x32_f16(a, b, acc, 0, 0, 0);
            }
        }
        if (ocol < 3) {
            #pragma unroll
            for (int r = 0; r < 4; ++r) {
                int row = wave * 16 + ((lane >> 4) << 2) + r;
                long gg = blkBase + (long)ci * 64 + row;
                if (gg < N) OUT[gg * 3 + ocol] = fabsf(acc[r] + b4v);
            }
        }
        // next iteration's lbar() drains this chunk's LDS reads before overwrite
    }
}

// ================= launch =================
extern "C" void kernel_launch(void* const* d_in, const int* in_sizes, int n_in,
                              void* d_out, int out_size, void* d_ws, size_t ws_size,
                              hipStream_t stream)
{
    const float* X   = (const float*)d_in[0];
    const float* WI  = (const float*)d_in[1];
    const float* NRM = (const float*)d_in[2];
    const float* FD  = (const float*)d_in[3];
    const float* TBL = (const float*)d_in[4];
    const float* W0  = (const float*)d_in[5];
    const float* B0  = (const float*)d_in[6];
    const float* W1  = (const float*)d_in[7];
    const float* B1  = (const float*)d_in[8];
    const float* W2  = (const float*)d_in[9];
    const float* B2  = (const float*)d_in[10];
    const float* W3  = (const float*)d_in[11];
    const float* B3  = (const float*)d_in[12];
    const float* W4  = (const float*)d_in[13];
    const float* B4  = (const float*)d_in[14];
    float* OUT = (float*)d_out;

    int N = in_sizes[0] / 3;
    _Float16* ws = (_Float16*)d_ws;
    uint32_t* tb8 = (uint32_t*)((char*)d_ws + TB8_BYTE_OFF);

    convert_weights<<<(PACK_TOTAL + 255) / 256, 256, 0, stream>>>(W0, W1, W2, W3, W4, ws);
    convert_table8<<<65536, 256, 0, stream>>>(TBL, (uint2*)tb8);

    const int NBLK = 512;                         // 2 blocks/CU
    int CH = (N + NBLK * 64 - 1) / (NBLK * 64);   // chunks per block (16 @ N=524288)

    hipFuncSetAttribute((const void*)nrfield_pipe,
                        hipFuncAttributeMaxDynamicSharedMemorySize, SMEM_BYTES);
    nrfield_pipe<<<NBLK, 256, SMEM_BYTES, stream>>>(X, WI, NRM, FD, tb8,
                                                    B0, B1, B2, B3, B4, ws,
                                                    OUT, N, CH);
}